// Round 4
// baseline (1194.480 us; speedup 1.0000x reference)
//
#include <hip/hip_runtime.h>
#include <stdint.h>

#define LN_EPS 1e-5f

// Grid-stride, software-pipelined: each thread handles ~5 rows. Half-row
// (8 x float4 = 128B) double buffering: while FMAs consume buffer A, the
// next 128B is loading into buffer B -> memory pipe continuously fed per
// wave (R3 failure: compiler sank loads, one latency exposure per chunk).
// sched_barrier(0) pins each load block before the compute that follows,
// preventing the R3 re-sinking. Weights stay wave-uniform -> s_load + fmac.
__global__ __launch_bounds__(256, 3) void dec_kernel(
    const float* __restrict__ x,
    const float* __restrict__ w1, const float* __restrict__ g1, const float* __restrict__ b1,
    const float* __restrict__ w2, const float* __restrict__ g2, const float* __restrict__ b2,
    const float* __restrict__ w3, const float* __restrict__ b3,
    float* __restrict__ out, int N, int HW)
{
  const int stride = gridDim.x * 256;
  int row = blockIdx.x * 256 + threadIdx.x;
  if (row >= N) return;

  float4 bufA[8], bufB[8];
  {
    const float4* __restrict__ xp = (const float4*)(x + (size_t)row * 64);
#pragma unroll
    for (int c = 0; c < 8; ++c) bufA[c] = xp[c];     // prologue: row0 first half
  }

  while (true) {
    const float4* __restrict__ xc = (const float4*)(x + (size_t)row * 64);
    // issue current row second half into B (overlaps bufA compute)
#pragma unroll
    for (int c = 0; c < 8; ++c) bufB[c] = xc[c + 8];
    __builtin_amdgcn_sched_barrier(0);

    // ---- layer 1, k = 0..31 from bufA ----
    float acc[32];
#pragma unroll
    for (int j = 0; j < 32; ++j) acc[j] = 0.f;
#pragma unroll
    for (int c = 0; c < 8; ++c) {
#pragma unroll
      for (int kk = 0; kk < 4; ++kk) {
        float xk = (kk == 0) ? bufA[c].x : (kk == 1) ? bufA[c].y : (kk == 2) ? bufA[c].z : bufA[c].w;
        const float* wrow = w1 + (c * 4 + kk) * 32;   // wave-uniform -> s_load
#pragma unroll
        for (int j = 0; j < 32; ++j) acc[j] = fmaf(xk, wrow[j], acc[j]);
      }
    }

    // prefetch next row first half into A (overlaps bufB compute + epilogue)
    const int nrow = row + stride;
    {
      const int prow = (nrow < N) ? nrow : row;       // clamp: dead reload, harmless
      const float4* __restrict__ xn = (const float4*)(x + (size_t)prow * 64);
#pragma unroll
      for (int c = 0; c < 8; ++c) bufA[c] = xn[c];
    }
    __builtin_amdgcn_sched_barrier(0);

    // ---- layer 1, k = 32..63 from bufB ----
#pragma unroll
    for (int c = 0; c < 8; ++c) {
#pragma unroll
      for (int kk = 0; kk < 4; ++kk) {
        float xk = (kk == 0) ? bufB[c].x : (kk == 1) ? bufB[c].y : (kk == 2) ? bufB[c].z : bufB[c].w;
        const float* wrow = w1 + (32 + c * 4 + kk) * 32;
#pragma unroll
        for (int j = 0; j < 32; ++j) acc[j] = fmaf(xk, wrow[j], acc[j]);
      }
    }

    // ---- LayerNorm(32) + ReLU ----
    {
      float p0 = 0.f, p1 = 0.f, p2 = 0.f, p3 = 0.f;
#pragma unroll
      for (int j = 0; j < 32; j += 4) { p0 += acc[j]; p1 += acc[j+1]; p2 += acc[j+2]; p3 += acc[j+3]; }
      float mu = ((p0 + p1) + (p2 + p3)) * 0.03125f;
      float q0 = 0.f, q1 = 0.f, q2 = 0.f, q3 = 0.f;
#pragma unroll
      for (int j = 0; j < 32; j += 4) {
        float d0 = acc[j] - mu, d1 = acc[j+1] - mu, d2 = acc[j+2] - mu, d3 = acc[j+3] - mu;
        acc[j] = d0; acc[j+1] = d1; acc[j+2] = d2; acc[j+3] = d3;
        q0 = fmaf(d0, d0, q0); q1 = fmaf(d1, d1, q1); q2 = fmaf(d2, d2, q2); q3 = fmaf(d3, d3, q3);
      }
      float var = ((q0 + q1) + (q2 + q3)) * 0.03125f;
      float rs  = rsqrtf(var + LN_EPS);
#pragma unroll
      for (int j = 0; j < 32; ++j) {
        float t = acc[j] * rs;
        t = fmaf(t, g1[j], b1[j]);
        acc[j] = fmaxf(t, 0.f);
      }
    }

    // ---- layer 2: K=32 -> 16, LN + ReLU ----
    float a2[16];
#pragma unroll
    for (int j = 0; j < 16; ++j) a2[j] = 0.f;
#pragma unroll
    for (int k = 0; k < 32; ++k) {
      float hk = acc[k];
      const float* wrow = w2 + k * 16;
#pragma unroll
      for (int j = 0; j < 16; ++j) a2[j] = fmaf(hk, wrow[j], a2[j]);
    }
    {
      float p0 = 0.f, p1 = 0.f, p2 = 0.f, p3 = 0.f;
#pragma unroll
      for (int j = 0; j < 16; j += 4) { p0 += a2[j]; p1 += a2[j+1]; p2 += a2[j+2]; p3 += a2[j+3]; }
      float mu = ((p0 + p1) + (p2 + p3)) * 0.0625f;
      float q0 = 0.f, q1 = 0.f, q2 = 0.f, q3 = 0.f;
#pragma unroll
      for (int j = 0; j < 16; j += 4) {
        float d0 = a2[j] - mu, d1 = a2[j+1] - mu, d2 = a2[j+2] - mu, d3 = a2[j+3] - mu;
        a2[j] = d0; a2[j+1] = d1; a2[j+2] = d2; a2[j+3] = d3;
        q0 = fmaf(d0, d0, q0); q1 = fmaf(d1, d1, q1); q2 = fmaf(d2, d2, q2); q3 = fmaf(d3, d3, q3);
      }
      float var = ((q0 + q1) + (q2 + q3)) * 0.0625f;
      float rs  = rsqrtf(var + LN_EPS);
#pragma unroll
      for (int j = 0; j < 16; ++j) {
        float t = a2[j] * rs;
        t = fmaf(t, g2[j], b2[j]);
        a2[j] = fmaxf(t, 0.f);
      }
    }

    // ---- layer 3 + channel L2-normalize ----
    float o0 = b3[0], o1 = b3[1], o2 = b3[2];
#pragma unroll
    for (int k = 0; k < 16; ++k) {
      float hk = a2[k];
      o0 = fmaf(hk, w3[k * 3 + 0], o0);
      o1 = fmaf(hk, w3[k * 3 + 1], o1);
      o2 = fmaf(hk, w3[k * 3 + 2], o2);
    }
    float nsq = fmaf(o0, o0, fmaf(o1, o1, o2 * o2));
    float inv = rsqrtf(fmaxf(nsq, 1e-24f));   // 1/max(||o||,1e-12)
    o0 *= inv; o1 *= inv; o2 *= inv;

    // out[b][c][h][w]; lanes consecutive in p -> coalesced per channel
    int b = (int)((unsigned)row / (unsigned)HW);
    int p = row - b * HW;
    size_t obase = (size_t)b * 3 * HW + p;
    out[obase]          = o0;
    out[obase + HW]     = o1;
    out[obase + 2 * HW] = o2;

    if (nrow >= N) break;
    row = nrow;
  }
}

extern "C" void kernel_launch(void* const* d_in, const int* in_sizes, int n_in,
                              void* d_out, int out_size, void* d_ws, size_t ws_size,
                              hipStream_t stream) {
  const float* x  = (const float*)d_in[0];
  const float* w1 = (const float*)d_in[1];
  const float* g1 = (const float*)d_in[2];
  const float* b1 = (const float*)d_in[3];
  const float* w2 = (const float*)d_in[4];
  const float* g2 = (const float*)d_in[5];
  const float* b2 = (const float*)d_in[6];
  const float* w3 = (const float*)d_in[7];
  const float* b3 = (const float*)d_in[8];
  float* out = (float*)d_out;

  const int N  = in_sizes[0] / 64;  // rows
  const int HW = N / 4;             // B = 4 per reference setup
  // 1024 blocks = 4096 waves; ~5 rows/thread -> pipeline steady state,
  // ~1.3x oversubscription at 3-4 waves/SIMD residency.
  int nblocks = 1024;
  const int maxb = (N + 255) / 256;
  if (nblocks > maxb) nblocks = maxb;
  dec_kernel<<<nblocks, 256, 0, stream>>>(x, w1, g1, b1, w2, g2, b2, w3, b3, out, N, HW);
}